// Round 5
// baseline (1134.873 us; speedup 1.0000x reference)
//
#include <hip/hip_runtime.h>
#include <stdint.h>

typedef unsigned short u16;
typedef float floatx4 __attribute__((ext_vector_type(4)));
typedef __bf16 bf16x8 __attribute__((ext_vector_type(8)));
typedef float f32x4v __attribute__((ext_vector_type(4)));
typedef unsigned u32x4v __attribute__((ext_vector_type(4)));

#define NUM_AREAS 4
#define AN 2048
#define NTOT 8192
#define BATCH 512
#define DIN 1024
#define NCLS 1024
#define THRESHOLD 0.05f
#define BAN (BATCH * AN)  // 1048576 elems per (area) slab

// ---- packed tile layout (bf16): tile = [256 rows][32 k] = 8192 elems = 16 KiB
// A (z):    [area][mb 2][kt 64][8192]   row = b = mb*256 + r, k = n_in = kt*32 + kk
// B (weff): [o4i 16][nb 8][kt 64][8192] row = n_out = nb*256 + r, k = n_in
// Staging a tile = 2 contiguous 8 KiB reads -> perfectly coalesced, line-aligned,
// DRAM-sequential (fixes the 64B-chunk stride-4096 latency pathology).
__device__ __forceinline__ size_t zpk(int a, int b, int n) {
    return ((((size_t)a * 2 + (b >> 8)) * 64 + (n >> 5)) << 13) | ((b & 255) << 5) | (n & 31);
}

__device__ __forceinline__ u16 f2bf(float f) {
    union { float f; unsigned u; } v; v.f = f;
    unsigned r = v.u + 0x7fffu + ((v.u >> 16) & 1u);  // RNE
    return (u16)(r >> 16);
}

__device__ __forceinline__ void load_lds16(const u16* g, u16* l) {
    __builtin_amdgcn_global_load_lds((const __attribute__((address_space(1))) void*)g,
                                     (__attribute__((address_space(3))) void*)l,
                                     16, 0, 0);
}

// ---- 128x128 bf16 GEMM core, depth-1 double-buffered (used by k_enc/k_out) ----
__device__ __forceinline__ void gemm_db(const u16* __restrict__ A, int lda,
                                        const u16* __restrict__ Bm, int ldb,
                                        int klen, u16* sA, u16* sB,
                                        floatx4 acc[4][4]) {
    const int tid = threadIdx.x;
    const int t8 = tid * 8;
    const int lane = tid & 63;
    const int quad = lane >> 4;
    const int l15 = lane & 15;
    const int wm = ((tid >> 7) & 1) * 64;
    const int wn = ((tid >> 6) & 1) * 64;
    const int r0 = t8 >> 5;
    const int kk = t8 & 31;
    const int nst = klen >> 5;

    auto stage = [&](int buf, int k0) {
        const int bo = buf << 12;
        load_lds16(A + (size_t)r0 * lda + (k0 + kk), sA + bo + t8);
        load_lds16(Bm + (size_t)r0 * ldb + (k0 + kk), sB + bo + t8);
        load_lds16(A + (size_t)(r0 + 64) * lda + (k0 + kk), sA + bo + 2048 + t8);
        load_lds16(Bm + (size_t)(r0 + 64) * ldb + (k0 + kk), sB + bo + 2048 + t8);
    };

    stage(0, 0);
    __syncthreads();
    int buf = 0;
    for (int t = 0; t < nst; ++t) {
        const int bo = buf << 12;
        bf16x8 av[4], bv[4];
#pragma unroll
        for (int i = 0; i < 4; ++i)
            av[i] = *(const bf16x8*)(sA + bo + (wm + i * 16 + l15) * 32 + quad * 8);
#pragma unroll
        for (int i = 0; i < 4; ++i)
            bv[i] = *(const bf16x8*)(sB + bo + (wn + i * 16 + l15) * 32 + quad * 8);
        if (t + 1 < nst) stage(buf ^ 1, (t + 1) << 5);
#pragma unroll
        for (int mt = 0; mt < 4; ++mt)
#pragma unroll
            for (int nt = 0; nt < 4; ++nt)
                acc[mt][nt] = __builtin_amdgcn_mfma_f32_16x16x32_bf16(av[mt], bv[nt], acc[mt][nt], 0, 0, 0);
        __syncthreads();
        buf ^= 1;
    }
}

// ---- init: logits = Ob broadcast, gate accumulators = 0 ----
__global__ void k_init(const float* __restrict__ Ob, float* __restrict__ out,
                       float* __restrict__ gacc) {
    const int i = blockIdx.x * 256 + threadIdx.x;
    if (i < BATCH * NCLS) out[i] = Ob[i & (NCLS - 1)];
    if (i < 32) gacc[i] = 0.f;
}

// ---- f32 -> bf16 bulk convert (8 elems/thread) ----
__global__ void k_cvt(const float* __restrict__ src, u16* __restrict__ dst, int n8) {
    const int i = blockIdx.x * 256 + threadIdx.x;
    if (i >= n8) return;
    const float4 x0 = ((const float4*)src)[2 * i];
    const float4 x1 = ((const float4*)src)[2 * i + 1];
    uint4 o;
    o.x = (unsigned)f2bf(x0.x) | ((unsigned)f2bf(x0.y) << 16);
    o.y = (unsigned)f2bf(x0.z) | ((unsigned)f2bf(x0.w) << 16);
    o.z = (unsigned)f2bf(x1.x) | ((unsigned)f2bf(x1.y) << 16);
    o.w = (unsigned)f2bf(x1.z) | ((unsigned)f2bf(x1.w) << 16);
    ((uint4*)dst)[i] = o;
}

#define CLM(m) fminf(fmaxf((m), 0.f), 1.f)
#define PKW(wa, ma, wb, mb) ((unsigned)f2bf((wa) * CLM(ma)) | ((unsigned)f2bf((wb) * CLM(mb)) << 16))

// ---- Weff = W * clamp(mask,0,1) -> bf16, PACKED tile-major output ----
// grid (16 ktg, 8 nb, 16 o4i), 256 thr. Writes each 16 KiB tile contiguously.
__global__ void k_weffp(const float* __restrict__ W, const float* __restrict__ mask,
                        u16* __restrict__ dst) {
    const int ktg = blockIdx.x, nb = blockIdx.y, o4i = blockIdx.z;
    const int t = threadIdx.x;
    u16* dt = dst + (((size_t)o4i * 8 + nb) * 64 + (size_t)ktg * 4) * 8192;
    const float* Wb = W + ((size_t)o4i * 2048 + nb * 256) * 2048;
    const float* Mb = mask + ((size_t)o4i * 2048 + nb * 256) * 2048;
    const int kk = (t & 3) * 8;
    const int rb = t >> 2;               // 0..63
#pragma unroll
    for (int s = 0; s < 4; ++s) {
        const int k0 = (ktg * 4 + s) * 32 + kk;
#pragma unroll
        for (int v = 0; v < 4; ++v) {
            const int r = v * 64 + rb;
            const float4* wp = (const float4*)(Wb + (size_t)r * 2048 + k0);
            const float4* mp = (const float4*)(Mb + (size_t)r * 2048 + k0);
            const float4 w0 = wp[0], w1 = wp[1];
            const float4 m0 = mp[0], m1 = mp[1];
            uint4 ov;
            ov.x = PKW(w0.x, m0.x, w0.y, m0.y);
            ov.y = PKW(w0.z, m0.z, w0.w, m0.w);
            ov.z = PKW(w1.x, m1.x, w1.y, m1.y);
            ov.w = PKW(w1.z, m1.z, w1.w, m1.w);
            *(uint4*)(dt + (size_t)s * 8192 + (size_t)v * 2048 + t * 8) = ov;
        }
    }
}

// ---- encoder: Z0 = tanh(x @ Rw^T + rb), write hist[0], z0 (PACKED bf16), gates ----
__global__ void k_enc(const u16* __restrict__ xbf, const u16* __restrict__ rwbf,
                      const float* __restrict__ rb, float* __restrict__ hist0,
                      u16* __restrict__ z0, float* __restrict__ gacc) {
    __shared__ __align__(16) u16 smemA[8192];
    __shared__ __align__(16) u16 smemB[8192];
    __shared__ float red[4];
    floatx4 acc[4][4] = {};
    const int mb = blockIdx.y, nb = blockIdx.x;
    gemm_db(xbf + (size_t)mb * 128 * DIN, DIN,
            rwbf + (size_t)nb * 128 * DIN, DIN, DIN, smemA, smemB, acc);
    const int tid = threadIdx.x, lane = tid & 63, quad = lane >> 4, l15 = lane & 15;
    const int wm = ((tid >> 7) & 1) * 64, wn = ((tid >> 6) & 1) * 64;
    const int cbase = nb * 128;
    const int area = cbase >> 11;
    float asum = 0.f;
#pragma unroll
    for (int nt = 0; nt < 4; ++nt) {
        const int col = cbase + wn + nt * 16 + l15;
        const int n = col & (AN - 1);
        const float bias = rb[col];
#pragma unroll
        for (int mt = 0; mt < 4; ++mt) {
#pragma unroll
            for (int r = 0; r < 4; ++r) {
                const int row = mb * 128 + wm + mt * 16 + quad * 4 + r;
                const float z = tanhf(acc[mt][nt][r] + bias);
                asum += fabsf(z);
                hist0[(size_t)area * BAN + (size_t)row * AN + n] = z;
                z0[zpk(area, row, n)] = f2bf(z);
            }
        }
    }
    for (int off = 32; off > 0; off >>= 1) asum += __shfl_down(asum, off, 64);
    if (lane == 0) red[tid >> 6] = asum;
    __syncthreads();
    if (tid == 0) atomicAdd(&gacc[area], red[0] + red[1] + red[2] + red[3]);
}

// ---- tick GEMM: 256x256 tile, 8 waves, BK=32, 3-slot ring, counted vmcnt(4),
//      PACKED operands (all staging reads fully contiguous). 1 block/CU.
//      zacc[i][o] = Z_prev[i] @ Weff[o,i]^T ; grid (32 nb, 2 mb, 4 i).
__global__ __launch_bounds__(512, 2)
void k_tick_mm(const u16* __restrict__ zprev, const u16* __restrict__ weff,
               const float* __restrict__ gin, float* __restrict__ zacc) {
    __shared__ __align__(16) u16 sA[3][8192];
    __shared__ __align__(16) u16 sB[3][8192];
    const int nb = blockIdx.x, mb = blockIdx.y, i = blockIdx.z;
    const float thr = THRESHOLD * (float)BAN;
    if (!(gin[i] > thr)) return;               // block-uniform; stale slice never read

    const int o = nb >> 3;
    const int nb8 = nb & 7;
    const int nbase = nb8 * 256;
    const int tid = threadIdx.x;
    const int lane = tid & 63, quad = lane >> 4, l15 = lane & 15;
    const int w = tid >> 6;
    const int wm = (w >> 2) * 128;
    const int wn = (w & 3) * 64;

    // packed bases (+ per-thread 16B offset); tile kt at +kt*8192 elems
    const u16* Ap = zprev + ((size_t)(i * 2 + mb) * 64) * 8192 + tid * 8;
    const u16* Bp = weff + ((size_t)((o * 4 + i) * 8 + nb8) * 64) * 8192 + tid * 8;
    u16* dA = &sA[0][tid * 8];
    u16* dB = &sB[0][tid * 8];

    auto stage = [&](int slot, int kt) {
        const size_t go = (size_t)kt * 8192;
        const int so = slot * 8192;
        load_lds16(Ap + go, dA + so);
        load_lds16(Ap + go + 4096, dA + so + 4096);
        load_lds16(Bp + go, dB + so);
        load_lds16(Bp + go + 4096, dB + so + 4096);
    };

    floatx4 acc[8][4] = {};

    stage(0, 0);
    stage(1, 1);
    asm volatile("s_waitcnt vmcnt(4)" ::: "memory");   // tile 0 landed; tile 1 in flight
    __builtin_amdgcn_s_barrier();

    const int NKT = AN / 32;                   // 64 K-tiles (K=2048)
    for (int kt = 0; kt < NKT; ++kt) {
        if (kt + 2 < NKT) stage((kt + 2) % 3, kt + 2);   // depth-2 prefetch
        const int sl = kt % 3;
        bf16x8 av[8], bv[4];
#pragma unroll
        for (int mt = 0; mt < 8; ++mt)
            av[mt] = *(const bf16x8*)(&sA[sl][(wm + mt * 16 + l15) * 32 + quad * 8]);
#pragma unroll
        for (int nt = 0; nt < 4; ++nt)
            bv[nt] = *(const bf16x8*)(&sB[sl][(wn + nt * 16 + l15) * 32 + quad * 8]);
        __builtin_amdgcn_s_setprio(1);
#pragma unroll
        for (int mt = 0; mt < 8; ++mt)
#pragma unroll
            for (int nt = 0; nt < 4; ++nt)
                acc[mt][nt] = __builtin_amdgcn_mfma_f32_16x16x32_bf16(av[mt], bv[nt], acc[mt][nt], 0, 0, 0);
        __builtin_amdgcn_s_setprio(0);
        if (kt < NKT - 2) {
            asm volatile("s_waitcnt vmcnt(4)" ::: "memory");  // retire tile kt+1's loads
        } else {
            asm volatile("s_waitcnt vmcnt(0)" ::: "memory");
        }
        __builtin_amdgcn_s_barrier();
    }

    float* __restrict__ dst = zacc + ((size_t)i * 4 + o) * BAN;
#pragma unroll
    for (int mt = 0; mt < 8; ++mt) {
#pragma unroll
        for (int nt = 0; nt < 4; ++nt) {
            const int n = nbase + wn + nt * 16 + l15;
#pragma unroll
            for (int r = 0; r < 4; ++r) {
                const int row = mb * 256 + wm + mt * 16 + quad * 4 + r;
                dst[(size_t)row * AN + n] = acc[mt][nt][r];
            }
        }
    }
}

// ---- tick epilogue: Z = tanh(sum_i gate[i]*zacc[i][o] + gated bias); hist row-major,
//      zcur PACKED bf16, per-area |Z| sums ----
__global__ void k_tick_ep(const float* __restrict__ zacc, const float* __restrict__ bblk,
                          const float* __restrict__ gin, float* __restrict__ hist,
                          u16* __restrict__ zcur, float* __restrict__ gout) {
    __shared__ float red[4];
    const int tid = threadIdx.x;
    const int t8 = (blockIdx.x * 256 + tid) * 8;   // elem index in [o][b][n]
    const int o = t8 >> 20;                        // block-uniform
    const int n = t8 & (AN - 1);
    const int io = t8 & (BAN - 1);                 // b*AN + n
    const int b = io >> 11;
    const float thr = THRESHOLD * (float)BAN;
    float s[8] = {0.f, 0.f, 0.f, 0.f, 0.f, 0.f, 0.f, 0.f};
#pragma unroll
    for (int i = 0; i < 4; ++i) {
        if (!(gin[i] > thr)) continue;
        const float4* p = (const float4*)(zacc + ((size_t)i * 4 + o) * BAN + io);
        const float4 x0 = p[0], x1 = p[1];
        const float4* bb = (const float4*)(bblk + (size_t)(o * 4 + i) * AN + n);
        const float4 b0 = bb[0], b1 = bb[1];
        s[0] += x0.x + b0.x; s[1] += x0.y + b0.y; s[2] += x0.z + b0.z; s[3] += x0.w + b0.w;
        s[4] += x1.x + b1.x; s[5] += x1.y + b1.y; s[6] += x1.z + b1.z; s[7] += x1.w + b1.w;
    }
    float4 h0, h1;
    uint4 zb;
    const float z0 = tanhf(s[0]), z1 = tanhf(s[1]), z2 = tanhf(s[2]), z3 = tanhf(s[3]);
    const float z4 = tanhf(s[4]), z5 = tanhf(s[5]), z6 = tanhf(s[6]), z7 = tanhf(s[7]);
    float asum = fabsf(z0) + fabsf(z1) + fabsf(z2) + fabsf(z3)
               + fabsf(z4) + fabsf(z5) + fabsf(z6) + fabsf(z7);
    h0.x = z0; h0.y = z1; h0.z = z2; h0.w = z3;
    h1.x = z4; h1.y = z5; h1.z = z6; h1.w = z7;
    zb.x = (unsigned)f2bf(z0) | ((unsigned)f2bf(z1) << 16);
    zb.y = (unsigned)f2bf(z2) | ((unsigned)f2bf(z3) << 16);
    zb.z = (unsigned)f2bf(z4) | ((unsigned)f2bf(z5) << 16);
    zb.w = (unsigned)f2bf(z6) | ((unsigned)f2bf(z7) << 16);
    ((float4*)(hist + t8))[0] = h0;
    ((float4*)(hist + t8))[1] = h1;
    *((uint4*)(zcur + zpk(o, b, n))) = zb;         // packed, 16B-aligned (n%8==0)
    for (int off = 32; off > 0; off >>= 1) asum += __shfl_down(asum, off, 64);
    if ((tid & 63) == 0) red[tid >> 6] = asum;
    __syncthreads();
    if (tid == 0) atomicAdd(&gout[o], red[0] + red[1] + red[2] + red[3]);
}

// ---- scatter PACKED Z -> Zflat[b, area_idx[a,n]] (bf16) ----
__global__ void k_scatter(const u16* __restrict__ z4, const int* __restrict__ aidx,
                          u16* __restrict__ zflat) {
    const int i = blockIdx.x * 256 + threadIdx.x;  // packed elem idx, 2^22 total
    const int a = i >> 20;
    const int rest = i & (BAN - 1);
    const int tile = rest >> 13;                   // mb*64 + kt
    const int within = rest & 8191;
    const int b = ((tile >> 6) << 8) | (within >> 5);
    const int n = ((tile & 63) << 5) | (within & 31);
    const int j = aidx[a * AN + n];
    zflat[(size_t)b * NTOT + j] = z4[i];
}

// ---- logits += Zflat @ Ow^T (split-K=8, atomic f32) ----
__global__ void k_out(const u16* __restrict__ zflat, const u16* __restrict__ owbf,
                      float* __restrict__ out) {
    __shared__ __align__(16) u16 smemA[8192];
    __shared__ __align__(16) u16 smemB[8192];
    floatx4 acc[4][4] = {};
    const int nb = blockIdx.x, mb = blockIdx.y, ks = blockIdx.z;
    gemm_db(zflat + (size_t)mb * 128 * NTOT + ks * 1024, NTOT,
            owbf + (size_t)nb * 128 * NTOT + ks * 1024, NTOT, 1024,
            smemA, smemB, acc);
    const int tid = threadIdx.x, lane = tid & 63, quad = lane >> 4, l15 = lane & 15;
    const int wm = ((tid >> 7) & 1) * 64, wn = ((tid >> 6) & 1) * 64;
#pragma unroll
    for (int mt = 0; mt < 4; ++mt)
#pragma unroll
        for (int nt = 0; nt < 4; ++nt)
#pragma unroll
            for (int r = 0; r < 4; ++r) {
                const int row = mb * 128 + wm + mt * 16 + quad * 4 + r;
                const int col = nb * 128 + wn + nt * 16 + l15;
                atomicAdd(&out[(size_t)row * NCLS + col], acc[mt][nt][r]);
            }
}

extern "C" void kernel_launch(void* const* d_in, const int* in_sizes, int n_in,
                              void* d_out, int out_size, void* d_ws, size_t ws_size,
                              hipStream_t stream) {
    (void)in_sizes; (void)n_in; (void)out_size; (void)ws_size;
    const float* x    = (const float*)d_in[0];
    const float* Rw   = (const float*)d_in[1];
    const float* rb   = (const float*)d_in[2];
    const float* Wb   = (const float*)d_in[3];
    const float* bblk = (const float*)d_in[4];
    const float* mask = (const float*)d_in[5];
    const float* Ow   = (const float*)d_in[6];
    const float* Ob   = (const float*)d_in[7];
    const int*   aidx = (const int*)d_in[8];

    float* out  = (float*)d_out;
    float* hist = out + (size_t)BATCH * NCLS;  // history: [5, 4, 512, 2048]

    char* ws = (char*)d_ws;
    size_t off = 0;
    auto alloc = [&](size_t bytes) -> char* {
        char* p = ws + off;
        off += (bytes + 255) & ~(size_t)255;
        return p;
    };
    u16* weffbf = (u16*)alloc((size_t)16 * AN * AN * 2);      // 128 MiB (packed tiles)
    // zacc: [4 i][4 o][512][2048] f32 split-K slices = 67.1 MiB.
    // Aliased over rwbf/owbf/zflat (live only OUTSIDE the tick loop).
    float* zacc = (float*)alloc((size_t)16 * BAN * 4);        // 67.1 MiB
    u16* rwbf  = (u16*)zacc;                                  // [0, 16 MiB)
    u16* owbf  = (u16*)((char*)zacc + ((size_t)16 << 20));    // [16, 32 MiB)
    u16* zflat = (u16*)((char*)zacc + ((size_t)32 << 20));    // [32, 40 MiB)
    u16* xbf    = (u16*)alloc((size_t)BATCH * DIN * 2);       // 1 MiB
    u16* zb0    = (u16*)alloc((size_t)NUM_AREAS * BAN * 2);   // 8 MiB (packed)
    u16* zb1    = (u16*)alloc((size_t)NUM_AREAS * BAN * 2);   // 8 MiB (packed)
    float* gacc = (float*)alloc(32 * 4);                      // [5][4] sums of |Z|
    u16* zb[2]  = { zb0, zb1 };

    k_init<<<(BATCH * NCLS + 255) / 256, 256, 0, stream>>>(Ob, out, gacc);
    k_cvt<<<(BATCH * DIN / 8) / 256, 256, 0, stream>>>(x, xbf, BATCH * DIN / 8);
    k_cvt<<<(NTOT * DIN / 8) / 256, 256, 0, stream>>>(Rw, rwbf, NTOT * DIN / 8);
    k_weffp<<<dim3(16, 8, 16), 256, 0, stream>>>(Wb, mask, weffbf);

    dim3 g1(64, 4);
    k_enc<<<g1, 256, 0, stream>>>(xbf, rwbf, rb, hist, zb[0], gacc);
    dim3 gmm(32, 2, 4);                                       // 256 blocks, 1/CU
    for (int t = 1; t <= 4; ++t) {
        k_tick_mm<<<gmm, 512, 0, stream>>>(zb[(t + 1) & 1], weffbf,
                                           gacc + (t - 1) * 4, zacc);
        k_tick_ep<<<2048, 256, 0, stream>>>(zacc, bblk, gacc + (t - 1) * 4,
                                            hist + (size_t)t * NUM_AREAS * BAN,
                                            zb[t & 1], gacc + t * 4);
    }
    // owbf/zflat alias zacc -> convert Ow only after ticks are done
    k_cvt<<<(NCLS * NTOT / 8) / 256, 256, 0, stream>>>(Ow, owbf, NCLS * NTOT / 8);
    // final Z is in zb[0] after 4 ticks
    k_scatter<<<(NUM_AREAS * BAN) / 256, 256, 0, stream>>>(zb[0], aidx, zflat);
    k_out<<<dim3(8, 4, 8), 256, 0, stream>>>(zflat, owbf, out);
}

// Round 6
// 1121.506 us; speedup vs baseline: 1.0119x; 1.0119x over previous
//
#include <hip/hip_runtime.h>
#include <stdint.h>

typedef unsigned short u16;
typedef float floatx4 __attribute__((ext_vector_type(4)));
typedef __bf16 bf16x8 __attribute__((ext_vector_type(8)));
typedef float f32x4v __attribute__((ext_vector_type(4)));
typedef unsigned u32x4v __attribute__((ext_vector_type(4)));

#define NUM_AREAS 4
#define AN 2048
#define NTOT 8192
#define BATCH 512
#define DIN 1024
#define NCLS 1024
#define THRESHOLD 0.05f
#define BAN (BATCH * AN)  // 1048576 elems per (area) slab

// ---- packed tile layout (bf16): tile = [256 rows][32 k] = 8192 elems = 16 KiB
// A (z):    [area][mb 2][kt 64][8192]   row = b = mb*256 + r, k = n_in = kt*32 + kk
// B (weff): [o4i 16][nb 8][kt 64][8192] row = n_out = nb*256 + r, k = n_in
__device__ __forceinline__ size_t zpk(int a, int b, int n) {
    return ((((size_t)a * 2 + (b >> 8)) * 64 + (n >> 5)) << 13) | ((b & 255) << 5) | (n & 31);
}

// ---- LDS bank-conflict swizzle (T2 via rule 21: linear LDS dest for gload_lds,
// pre-swizzled GLOBAL source + swizzled ds_read). Involution on 16B chunks:
//   swz(c) = c ^ ((c>>3)&3)   (permutes chunks WITHIN each 128B line -> coalescing kept)
// Fragment read of G-chunk row*4+quad lives at LDS chunk row*4+(quad^((row>>1)&3)).
// Pre-swizzle: the old pattern put 16 lanes on 2 of 8 bank-groups (8-way conflict,
// ~35cy/ds_read_b128 -> LDS pipe was the critical path, ~90us/tick). Post: all 8
// groups, 2 lanes each (free).

__device__ __forceinline__ u16 f2bf(float f) {
    union { float f; unsigned u; } v; v.f = f;
    unsigned r = v.u + 0x7fffu + ((v.u >> 16) & 1u);  // RNE
    return (u16)(r >> 16);
}

__device__ __forceinline__ void load_lds16(const u16* g, u16* l) {
    __builtin_amdgcn_global_load_lds((const __attribute__((address_space(1))) void*)g,
                                     (__attribute__((address_space(3))) void*)l,
                                     16, 0, 0);
}

// ---- 128x128 bf16 GEMM core, depth-1 double-buffered, swizzled LDS ----
__device__ __forceinline__ void gemm_db(const u16* __restrict__ A, int lda,
                                        const u16* __restrict__ Bm, int ldb,
                                        int klen, u16* sA, u16* sB,
                                        floatx4 acc[4][4]) {
    const int tid = threadIdx.x;
    const int t8 = tid * 8;
    const int lane = tid & 63;
    const int quad = lane >> 4;
    const int l15 = lane & 15;
    const int qs8 = (quad ^ ((l15 >> 1) & 3)) * 8;          // swizzled read offset
    const int wm = ((tid >> 7) & 1) * 64;
    const int wn = ((tid >> 6) & 1) * 64;
    const int r0 = t8 >> 5;
    const int kks = (((tid & 3) ^ ((tid >> 3) & 3)) << 3);  // swizzled source k-offset
    const int nst = klen >> 5;

    auto stage = [&](int buf, int k0) {
        const int bo = buf << 12;
        load_lds16(A + (size_t)r0 * lda + (k0 + kks), sA + bo + t8);
        load_lds16(Bm + (size_t)r0 * ldb + (k0 + kks), sB + bo + t8);
        load_lds16(A + (size_t)(r0 + 64) * lda + (k0 + kks), sA + bo + 2048 + t8);
        load_lds16(Bm + (size_t)(r0 + 64) * ldb + (k0 + kks), sB + bo + 2048 + t8);
    };

    stage(0, 0);
    __syncthreads();
    int buf = 0;
    for (int t = 0; t < nst; ++t) {
        const int bo = buf << 12;
        bf16x8 av[4], bv[4];
#pragma unroll
        for (int i = 0; i < 4; ++i)
            av[i] = *(const bf16x8*)(sA + bo + (wm + i * 16 + l15) * 32 + qs8);
#pragma unroll
        for (int i = 0; i < 4; ++i)
            bv[i] = *(const bf16x8*)(sB + bo + (wn + i * 16 + l15) * 32 + qs8);
        if (t + 1 < nst) stage(buf ^ 1, (t + 1) << 5);
#pragma unroll
        for (int mt = 0; mt < 4; ++mt)
#pragma unroll
            for (int nt = 0; nt < 4; ++nt)
                acc[mt][nt] = __builtin_amdgcn_mfma_f32_16x16x32_bf16(av[mt], bv[nt], acc[mt][nt], 0, 0, 0);
        __syncthreads();
        buf ^= 1;
    }
}

// ---- init: logits = Ob broadcast, gate accumulators = 0 ----
__global__ void k_init(const float* __restrict__ Ob, float* __restrict__ out,
                       float* __restrict__ gacc) {
    const int i = blockIdx.x * 256 + threadIdx.x;
    if (i < BATCH * NCLS) out[i] = Ob[i & (NCLS - 1)];
    if (i < 32) gacc[i] = 0.f;
}

// ---- f32 -> bf16 bulk convert (8 elems/thread) ----
__global__ void k_cvt(const float* __restrict__ src, u16* __restrict__ dst, int n8) {
    const int i = blockIdx.x * 256 + threadIdx.x;
    if (i >= n8) return;
    const float4 x0 = ((const float4*)src)[2 * i];
    const float4 x1 = ((const float4*)src)[2 * i + 1];
    uint4 o;
    o.x = (unsigned)f2bf(x0.x) | ((unsigned)f2bf(x0.y) << 16);
    o.y = (unsigned)f2bf(x0.z) | ((unsigned)f2bf(x0.w) << 16);
    o.z = (unsigned)f2bf(x1.x) | ((unsigned)f2bf(x1.y) << 16);
    o.w = (unsigned)f2bf(x1.z) | ((unsigned)f2bf(x1.w) << 16);
    ((uint4*)dst)[i] = o;
}

#define CLM(m) fminf(fmaxf((m), 0.f), 1.f)
#define PKW(wa, ma, wb, mb) ((unsigned)f2bf((wa) * CLM(ma)) | ((unsigned)f2bf((wb) * CLM(mb)) << 16))

// ---- Weff = W * clamp(mask,0,1) -> bf16, PACKED tile-major output ----
__global__ void k_weffp(const float* __restrict__ W, const float* __restrict__ mask,
                        u16* __restrict__ dst) {
    const int ktg = blockIdx.x, nb = blockIdx.y, o4i = blockIdx.z;
    const int t = threadIdx.x;
    u16* dt = dst + (((size_t)o4i * 8 + nb) * 64 + (size_t)ktg * 4) * 8192;
    const float* Wb = W + ((size_t)o4i * 2048 + nb * 256) * 2048;
    const float* Mb = mask + ((size_t)o4i * 2048 + nb * 256) * 2048;
    const int kk = (t & 3) * 8;
    const int rb = t >> 2;               // 0..63
#pragma unroll
    for (int s = 0; s < 4; ++s) {
        const int k0 = (ktg * 4 + s) * 32 + kk;
#pragma unroll
        for (int v = 0; v < 4; ++v) {
            const int r = v * 64 + rb;
            const float4* wp = (const float4*)(Wb + (size_t)r * 2048 + k0);
            const float4* mp = (const float4*)(Mb + (size_t)r * 2048 + k0);
            const float4 w0 = wp[0], w1 = wp[1];
            const float4 m0 = mp[0], m1 = mp[1];
            uint4 ov;
            ov.x = PKW(w0.x, m0.x, w0.y, m0.y);
            ov.y = PKW(w0.z, m0.z, w0.w, m0.w);
            ov.z = PKW(w1.x, m1.x, w1.y, m1.y);
            ov.w = PKW(w1.z, m1.z, w1.w, m1.w);
            *(uint4*)(dt + (size_t)s * 8192 + (size_t)v * 2048 + t * 8) = ov;
        }
    }
}

// ---- encoder: Z0 = tanh(x @ Rw^T + rb), write hist[0], z0 (PACKED bf16), gates ----
__global__ void k_enc(const u16* __restrict__ xbf, const u16* __restrict__ rwbf,
                      const float* __restrict__ rb, float* __restrict__ hist0,
                      u16* __restrict__ z0, float* __restrict__ gacc) {
    __shared__ __align__(16) u16 smemA[8192];
    __shared__ __align__(16) u16 smemB[8192];
    __shared__ float red[4];
    floatx4 acc[4][4] = {};
    const int mb = blockIdx.y, nb = blockIdx.x;
    gemm_db(xbf + (size_t)mb * 128 * DIN, DIN,
            rwbf + (size_t)nb * 128 * DIN, DIN, DIN, smemA, smemB, acc);
    const int tid = threadIdx.x, lane = tid & 63, quad = lane >> 4, l15 = lane & 15;
    const int wm = ((tid >> 7) & 1) * 64, wn = ((tid >> 6) & 1) * 64;
    const int cbase = nb * 128;
    const int area = cbase >> 11;
    float asum = 0.f;
#pragma unroll
    for (int nt = 0; nt < 4; ++nt) {
        const int col = cbase + wn + nt * 16 + l15;
        const int n = col & (AN - 1);
        const float bias = rb[col];
#pragma unroll
        for (int mt = 0; mt < 4; ++mt) {
#pragma unroll
            for (int r = 0; r < 4; ++r) {
                const int row = mb * 128 + wm + mt * 16 + quad * 4 + r;
                const float z = tanhf(acc[mt][nt][r] + bias);
                asum += fabsf(z);
                hist0[(size_t)area * BAN + (size_t)row * AN + n] = z;
                z0[zpk(area, row, n)] = f2bf(z);
            }
        }
    }
    for (int off = 32; off > 0; off >>= 1) asum += __shfl_down(asum, off, 64);
    if (lane == 0) red[tid >> 6] = asum;
    __syncthreads();
    if (tid == 0) atomicAdd(&gacc[area], red[0] + red[1] + red[2] + red[3]);
}

// ---- tick GEMM: 256x256 tile, 8 waves, BK=32, 3-slot ring, counted vmcnt(4),
//      PACKED operands + bank-swizzled LDS. grid (32 nb, 2 mb, 4 i), 1 block/CU.
__global__ __launch_bounds__(512, 2)
void k_tick_mm(const u16* __restrict__ zprev, const u16* __restrict__ weff,
               const float* __restrict__ gin, float* __restrict__ zacc) {
    __shared__ __align__(16) u16 sA[3][8192];
    __shared__ __align__(16) u16 sB[3][8192];
    const int nb = blockIdx.x, mb = blockIdx.y, i = blockIdx.z;
    const float thr = THRESHOLD * (float)BAN;
    if (!(gin[i] > thr)) return;               // block-uniform; stale slice never read

    const int o = nb >> 3;
    const int nb8 = nb & 7;
    const int nbase = nb8 * 256;
    const int tid = threadIdx.x;
    const int lane = tid & 63, quad = lane >> 4, l15 = lane & 15;
    const int qs8 = (quad ^ ((l15 >> 1) & 3)) * 8;     // swizzled read offset
    const int w = tid >> 6;
    const int wm = (w >> 2) * 128;
    const int wn = (w & 3) * 64;

    // pre-swizzled global source: chunk tid -> tid ^ ((tid>>3)&3)  (within 128B lines)
    const int swt = (tid ^ ((tid >> 3) & 3)) * 8;
    const u16* Ap = zprev + ((size_t)(i * 2 + mb) * 64) * 8192 + swt;
    const u16* Bp = weff + ((size_t)((o * 4 + i) * 8 + nb8) * 64) * 8192 + swt;
    u16* dA = &sA[0][tid * 8];
    u16* dB = &sB[0][tid * 8];

    auto stage = [&](int slot, int kt) {
        const size_t go = (size_t)kt * 8192;
        const int so = slot * 8192;
        load_lds16(Ap + go, dA + so);
        load_lds16(Ap + go + 4096, dA + so + 4096);
        load_lds16(Bp + go, dB + so);
        load_lds16(Bp + go + 4096, dB + so + 4096);
    };

    floatx4 acc[8][4] = {};

    stage(0, 0);
    stage(1, 1);
    asm volatile("s_waitcnt vmcnt(4)" ::: "memory");   // tile 0 landed; tile 1 in flight
    __builtin_amdgcn_s_barrier();

    const int NKT = AN / 32;                   // 64 K-tiles (K=2048)
    for (int kt = 0; kt < NKT; ++kt) {
        if (kt + 2 < NKT) stage((kt + 2) % 3, kt + 2);   // depth-2 prefetch
        const int sl = kt % 3;
        bf16x8 av[8], bv[4];
#pragma unroll
        for (int mt = 0; mt < 8; ++mt)
            av[mt] = *(const bf16x8*)(&sA[sl][(wm + mt * 16 + l15) * 32 + qs8]);
#pragma unroll
        for (int nt = 0; nt < 4; ++nt)
            bv[nt] = *(const bf16x8*)(&sB[sl][(wn + nt * 16 + l15) * 32 + qs8]);
        __builtin_amdgcn_s_setprio(1);
#pragma unroll
        for (int mt = 0; mt < 8; ++mt)
#pragma unroll
            for (int nt = 0; nt < 4; ++nt)
                acc[mt][nt] = __builtin_amdgcn_mfma_f32_16x16x32_bf16(av[mt], bv[nt], acc[mt][nt], 0, 0, 0);
        __builtin_amdgcn_s_setprio(0);
        if (kt < NKT - 2) {
            asm volatile("s_waitcnt vmcnt(4)" ::: "memory");  // retire tile kt+1's loads
        } else {
            asm volatile("s_waitcnt vmcnt(0)" ::: "memory");
        }
        __builtin_amdgcn_s_barrier();
    }

    float* __restrict__ dst = zacc + ((size_t)i * 4 + o) * BAN;
#pragma unroll
    for (int mt = 0; mt < 8; ++mt) {
#pragma unroll
        for (int nt = 0; nt < 4; ++nt) {
            const int n = nbase + wn + nt * 16 + l15;
#pragma unroll
            for (int r = 0; r < 4; ++r) {
                const int row = mb * 256 + wm + mt * 16 + quad * 4 + r;
                dst[(size_t)row * AN + n] = acc[mt][nt][r];
            }
        }
    }
}

// ---- tick epilogue: Z = tanh(sum_i gate[i]*zacc[i][o] + gated bias) ----
__global__ void k_tick_ep(const float* __restrict__ zacc, const float* __restrict__ bblk,
                          const float* __restrict__ gin, float* __restrict__ hist,
                          u16* __restrict__ zcur, float* __restrict__ gout) {
    __shared__ float red[4];
    const int tid = threadIdx.x;
    const int t8 = (blockIdx.x * 256 + tid) * 8;   // elem index in [o][b][n]
    const int o = t8 >> 20;                        // block-uniform
    const int n = t8 & (AN - 1);
    const int io = t8 & (BAN - 1);                 // b*AN + n
    const int b = io >> 11;
    const float thr = THRESHOLD * (float)BAN;
    float s[8] = {0.f, 0.f, 0.f, 0.f, 0.f, 0.f, 0.f, 0.f};
#pragma unroll
    for (int i = 0; i < 4; ++i) {
        if (!(gin[i] > thr)) continue;
        const float4* p = (const float4*)(zacc + ((size_t)i * 4 + o) * BAN + io);
        const float4 x0 = p[0], x1 = p[1];
        const float4* bb = (const float4*)(bblk + (size_t)(o * 4 + i) * AN + n);
        const float4 b0 = bb[0], b1 = bb[1];
        s[0] += x0.x + b0.x; s[1] += x0.y + b0.y; s[2] += x0.z + b0.z; s[3] += x0.w + b0.w;
        s[4] += x1.x + b1.x; s[5] += x1.y + b1.y; s[6] += x1.z + b1.z; s[7] += x1.w + b1.w;
    }
    float4 h0, h1;
    uint4 zb;
    const float z0 = tanhf(s[0]), z1 = tanhf(s[1]), z2 = tanhf(s[2]), z3 = tanhf(s[3]);
    const float z4 = tanhf(s[4]), z5 = tanhf(s[5]), z6 = tanhf(s[6]), z7 = tanhf(s[7]);
    float asum = fabsf(z0) + fabsf(z1) + fabsf(z2) + fabsf(z3)
               + fabsf(z4) + fabsf(z5) + fabsf(z6) + fabsf(z7);
    h0.x = z0; h0.y = z1; h0.z = z2; h0.w = z3;
    h1.x = z4; h1.y = z5; h1.z = z6; h1.w = z7;
    zb.x = (unsigned)f2bf(z0) | ((unsigned)f2bf(z1) << 16);
    zb.y = (unsigned)f2bf(z2) | ((unsigned)f2bf(z3) << 16);
    zb.z = (unsigned)f2bf(z4) | ((unsigned)f2bf(z5) << 16);
    zb.w = (unsigned)f2bf(z6) | ((unsigned)f2bf(z7) << 16);
    ((float4*)(hist + t8))[0] = h0;
    ((float4*)(hist + t8))[1] = h1;
    *((uint4*)(zcur + zpk(o, b, n))) = zb;         // packed, 16B-aligned (n%8==0)
    for (int off = 32; off > 0; off >>= 1) asum += __shfl_down(asum, off, 64);
    if ((tid & 63) == 0) red[tid >> 6] = asum;
    __syncthreads();
    if (tid == 0) atomicAdd(&gout[o], red[0] + red[1] + red[2] + red[3]);
}

// ---- scatter PACKED Z -> Zflat[b, area_idx[a,n]] (bf16) ----
__global__ void k_scatter(const u16* __restrict__ z4, const int* __restrict__ aidx,
                          u16* __restrict__ zflat) {
    const int i = blockIdx.x * 256 + threadIdx.x;  // packed elem idx, 2^22 total
    const int a = i >> 20;
    const int rest = i & (BAN - 1);
    const int tile = rest >> 13;                   // mb*64 + kt
    const int within = rest & 8191;
    const int b = ((tile >> 6) << 8) | (within >> 5);
    const int n = ((tile & 63) << 5) | (within & 31);
    const int j = aidx[a * AN + n];
    zflat[(size_t)b * NTOT + j] = z4[i];
}

// ---- logits += Zflat @ Ow^T (split-K=8, atomic f32) ----
__global__ void k_out(const u16* __restrict__ zflat, const u16* __restrict__ owbf,
                      float* __restrict__ out) {
    __shared__ __align__(16) u16 smemA[8192];
    __shared__ __align__(16) u16 smemB[8192];
    floatx4 acc[4][4] = {};
    const int nb = blockIdx.x, mb = blockIdx.y, ks = blockIdx.z;
    gemm_db(zflat + (size_t)mb * 128 * NTOT + ks * 1024, NTOT,
            owbf + (size_t)nb * 128 * NTOT + ks * 1024, NTOT, 1024,
            smemA, smemB, acc);
    const int tid = threadIdx.x, lane = tid & 63, quad = lane >> 4, l15 = lane & 15;
    const int wm = ((tid >> 7) & 1) * 64, wn = ((tid >> 6) & 1) * 64;
#pragma unroll
    for (int mt = 0; mt < 4; ++mt)
#pragma unroll
        for (int nt = 0; nt < 4; ++nt)
#pragma unroll
            for (int r = 0; r < 4; ++r) {
                const int row = mb * 128 + wm + mt * 16 + quad * 4 + r;
                const int col = nb * 128 + wn + nt * 16 + l15;
                atomicAdd(&out[(size_t)row * NCLS + col], acc[mt][nt][r]);
            }
}

extern "C" void kernel_launch(void* const* d_in, const int* in_sizes, int n_in,
                              void* d_out, int out_size, void* d_ws, size_t ws_size,
                              hipStream_t stream) {
    (void)in_sizes; (void)n_in; (void)out_size; (void)ws_size;
    const float* x    = (const float*)d_in[0];
    const float* Rw   = (const float*)d_in[1];
    const float* rb   = (const float*)d_in[2];
    const float* Wb   = (const float*)d_in[3];
    const float* bblk = (const float*)d_in[4];
    const float* mask = (const float*)d_in[5];
    const float* Ow   = (const float*)d_in[6];
    const float* Ob   = (const float*)d_in[7];
    const int*   aidx = (const int*)d_in[8];

    float* out  = (float*)d_out;
    float* hist = out + (size_t)BATCH * NCLS;  // history: [5, 4, 512, 2048]

    char* ws = (char*)d_ws;
    size_t off = 0;
    auto alloc = [&](size_t bytes) -> char* {
        char* p = ws + off;
        off += (bytes + 255) & ~(size_t)255;
        return p;
    };
    u16* weffbf = (u16*)alloc((size_t)16 * AN * AN * 2);      // 128 MiB (packed tiles)
    // zacc: [4 i][4 o][512][2048] f32 split-K slices = 67.1 MiB.
    // Aliased over rwbf/owbf/zflat (live only OUTSIDE the tick loop).
    float* zacc = (float*)alloc((size_t)16 * BAN * 4);        // 67.1 MiB
    u16* rwbf  = (u16*)zacc;                                  // [0, 16 MiB)
    u16* owbf  = (u16*)((char*)zacc + ((size_t)16 << 20));    // [16, 32 MiB)
    u16* zflat = (u16*)((char*)zacc + ((size_t)32 << 20));    // [32, 40 MiB)
    u16* xbf    = (u16*)alloc((size_t)BATCH * DIN * 2);       // 1 MiB
    u16* zb0    = (u16*)alloc((size_t)NUM_AREAS * BAN * 2);   // 8 MiB (packed)
    u16* zb1    = (u16*)alloc((size_t)NUM_AREAS * BAN * 2);   // 8 MiB (packed)
    float* gacc = (float*)alloc(32 * 4);                      // [5][4] sums of |Z|
    u16* zb[2]  = { zb0, zb1 };

    k_init<<<(BATCH * NCLS + 255) / 256, 256, 0, stream>>>(Ob, out, gacc);
    k_cvt<<<(BATCH * DIN / 8) / 256, 256, 0, stream>>>(x, xbf, BATCH * DIN / 8);
    k_cvt<<<(NTOT * DIN / 8) / 256, 256, 0, stream>>>(Rw, rwbf, NTOT * DIN / 8);
    k_weffp<<<dim3(16, 8, 16), 256, 0, stream>>>(Wb, mask, weffbf);

    dim3 g1(64, 4);
    k_enc<<<g1, 256, 0, stream>>>(xbf, rwbf, rb, hist, zb[0], gacc);
    dim3 gmm(32, 2, 4);                                       // 256 blocks, 1/CU
    for (int t = 1; t <= 4; ++t) {
        k_tick_mm<<<gmm, 512, 0, stream>>>(zb[(t + 1) & 1], weffbf,
                                           gacc + (t - 1) * 4, zacc);
        k_tick_ep<<<2048, 256, 0, stream>>>(zacc, bblk, gacc + (t - 1) * 4,
                                            hist + (size_t)t * NUM_AREAS * BAN,
                                            zb[t & 1], gacc + t * 4);
    }
    // owbf/zflat alias zacc -> convert Ow only after ticks are done
    k_cvt<<<(NCLS * NTOT / 8) / 256, 256, 0, stream>>>(Ow, owbf, NCLS * NTOT / 8);
    // final Z is in zb[0] after 4 ticks
    k_scatter<<<(NUM_AREAS * BAN) / 256, 256, 0, stream>>>(zb[0], aidx, zflat);
    k_out<<<dim3(8, 4, 8), 256, 0, stream>>>(zflat, owbf, out);
}

// Round 7
// 1083.218 us; speedup vs baseline: 1.0477x; 1.0353x over previous
//
#include <hip/hip_runtime.h>
#include <stdint.h>

typedef unsigned short u16;
typedef float floatx4 __attribute__((ext_vector_type(4)));
typedef __bf16 bf16x8 __attribute__((ext_vector_type(8)));
typedef float f32x4v __attribute__((ext_vector_type(4)));
typedef unsigned u32x4v __attribute__((ext_vector_type(4)));

#define NUM_AREAS 4
#define AN 2048
#define NTOT 8192
#define BATCH 512
#define DIN 1024
#define NCLS 1024
#define THRESHOLD 0.05f
#define BAN (BATCH * AN)  // 1048576 elems per (area) slab

// ---- packed tile layout v2 (bf16), tile = [128 rows][64 k] = 8192 elems = 16 KiB,
// with the LDS bank swizzle BAKED IN: within row r, 16B chunk c of the k-axis is
// stored at chunk position c ^ (r&7).  (T2 via rule 21: gload_lds stays linear,
// the source permutation and the ds_read permutation are the same involution.)
// A (z):    [area 4][rowblk 4 (=b>>7)][kt 32][tile]
// B (weff): [o4i 16][nblk 16 (=n_out>>7)][kt 32][tile]
__device__ __forceinline__ size_t zpk2(int a, int b, int n) {
    const int rowblk = b >> 7, r = b & 127, kt = n >> 6, k = n & 63;
    const int kc = ((k >> 3) ^ (r & 7));
    return ((((size_t)a * 4 + rowblk) * 32 + kt) << 13) + r * 64 + (kc << 3) + (k & 7);
}

__device__ __forceinline__ u16 f2bf(float f) {
    union { float f; unsigned u; } v; v.f = f;
    unsigned r = v.u + 0x7fffu + ((v.u >> 16) & 1u);  // RNE
    return (u16)(r >> 16);
}

__device__ __forceinline__ void load_lds16(const u16* g, u16* l) {
    __builtin_amdgcn_global_load_lds((const __attribute__((address_space(1))) void*)g,
                                     (__attribute__((address_space(3))) void*)l,
                                     16, 0, 0);
}

// ---- 128x128 bf16 GEMM core, depth-1 double-buffered (k_enc / k_out only) ----
__device__ __forceinline__ void gemm_db(const u16* __restrict__ A, int lda,
                                        const u16* __restrict__ Bm, int ldb,
                                        int klen, u16* sA, u16* sB,
                                        floatx4 acc[4][4]) {
    const int tid = threadIdx.x;
    const int t8 = tid * 8;
    const int lane = tid & 63;
    const int quad = lane >> 4;
    const int l15 = lane & 15;
    const int qs8 = (quad ^ ((l15 >> 1) & 3)) * 8;
    const int wm = ((tid >> 7) & 1) * 64;
    const int wn = ((tid >> 6) & 1) * 64;
    const int r0 = t8 >> 5;
    const int kks = (((tid & 3) ^ ((tid >> 3) & 3)) << 3);
    const int nst = klen >> 5;

    auto stage = [&](int buf, int k0) {
        const int bo = buf << 12;
        load_lds16(A + (size_t)r0 * lda + (k0 + kks), sA + bo + t8);
        load_lds16(Bm + (size_t)r0 * ldb + (k0 + kks), sB + bo + t8);
        load_lds16(A + (size_t)(r0 + 64) * lda + (k0 + kks), sA + bo + 2048 + t8);
        load_lds16(Bm + (size_t)(r0 + 64) * ldb + (k0 + kks), sB + bo + 2048 + t8);
    };

    stage(0, 0);
    __syncthreads();
    int buf = 0;
    for (int t = 0; t < nst; ++t) {
        const int bo = buf << 12;
        bf16x8 av[4], bv[4];
#pragma unroll
        for (int i = 0; i < 4; ++i)
            av[i] = *(const bf16x8*)(sA + bo + (wm + i * 16 + l15) * 32 + qs8);
#pragma unroll
        for (int i = 0; i < 4; ++i)
            bv[i] = *(const bf16x8*)(sB + bo + (wn + i * 16 + l15) * 32 + qs8);
        if (t + 1 < nst) stage(buf ^ 1, (t + 1) << 5);
#pragma unroll
        for (int mt = 0; mt < 4; ++mt)
#pragma unroll
            for (int nt = 0; nt < 4; ++nt)
                acc[mt][nt] = __builtin_amdgcn_mfma_f32_16x16x32_bf16(av[mt], bv[nt], acc[mt][nt], 0, 0, 0);
        __syncthreads();
        buf ^= 1;
    }
}

// ---- init ----
__global__ void k_init(const float* __restrict__ Ob, float* __restrict__ out,
                       float* __restrict__ gacc) {
    const int i = blockIdx.x * 256 + threadIdx.x;
    if (i < BATCH * NCLS) out[i] = Ob[i & (NCLS - 1)];
    if (i < 32) gacc[i] = 0.f;
}

// ---- f32 -> bf16 bulk convert (8 elems/thread) ----
__global__ void k_cvt(const float* __restrict__ src, u16* __restrict__ dst, int n8) {
    const int i = blockIdx.x * 256 + threadIdx.x;
    if (i >= n8) return;
    const float4 x0 = ((const float4*)src)[2 * i];
    const float4 x1 = ((const float4*)src)[2 * i + 1];
    uint4 o;
    o.x = (unsigned)f2bf(x0.x) | ((unsigned)f2bf(x0.y) << 16);
    o.y = (unsigned)f2bf(x0.z) | ((unsigned)f2bf(x0.w) << 16);
    o.z = (unsigned)f2bf(x1.x) | ((unsigned)f2bf(x1.y) << 16);
    o.w = (unsigned)f2bf(x1.z) | ((unsigned)f2bf(x1.w) << 16);
    ((uint4*)dst)[i] = o;
}

#define CLM(m) fminf(fmaxf((m), 0.f), 1.f)
#define PKW(wa, ma, wb, mb) ((unsigned)f2bf((wa) * CLM(ma)) | ((unsigned)f2bf((wb) * CLM(mb)) << 16))

// ---- Weff pack: CONTIGUOUS streaming reads (1 MiB/block region), swizzled tiles out.
// grid (4 rsub, 16 nblk, 16 o4i), 256 thr. Old version read 64B chunks @8KB stride
// (DRAM-pathological, 2.6 TB/s); this one reads rows sequentially.
__global__ void k_weffp(const float* __restrict__ W, const float* __restrict__ mask,
                        u16* __restrict__ dst) {
    const int rsub = blockIdx.x, nblk = blockIdx.y, o4i = blockIdx.z;
    const int t = threadIdx.x;
    const int gr0 = nblk * 128 + rsub * 32;
    const float* Wb = W + ((size_t)o4i * 2048 + gr0) * 2048;
    const float* Mb = mask + ((size_t)o4i * 2048 + gr0) * 2048;
    u16* dbase = dst + (((size_t)o4i * 16 + nblk) * 32) * 8192;
    const int kt = t >> 3;          // tile along k
    const int kc = t & 7;           // 16B chunk within tile-row
    for (int r = 0; r < 32; ++r) {
        const int rr = rsub * 32 + r;                 // row within 128-row tile
        const float4* wp = (const float4*)(Wb + (size_t)r * 2048 + t * 8);
        const float4* mp = (const float4*)(Mb + (size_t)r * 2048 + t * 8);
        const float4 w0 = wp[0], w1 = wp[1];
        const float4 m0 = mp[0], m1 = mp[1];
        uint4 ov;
        ov.x = PKW(w0.x, m0.x, w0.y, m0.y);
        ov.y = PKW(w0.z, m0.z, w0.w, m0.w);
        ov.z = PKW(w1.x, m1.x, w1.y, m1.y);
        ov.w = PKW(w1.z, m1.z, w1.w, m1.w);
        const int kcs = kc ^ (rr & 7);
        *(uint4*)(dbase + (size_t)kt * 8192 + rr * 64 + kcs * 8) = ov;
    }
}

// ---- encoder: Z0 = tanh(x @ Rw^T + rb) -> hist[0], z0 (packed v2), gate sums ----
__global__ void k_enc(const u16* __restrict__ xbf, const u16* __restrict__ rwbf,
                      const float* __restrict__ rb, float* __restrict__ hist0,
                      u16* __restrict__ z0, float* __restrict__ gacc) {
    __shared__ __align__(16) u16 smemA[8192];
    __shared__ __align__(16) u16 smemB[8192];
    __shared__ float red[4];
    floatx4 acc[4][4] = {};
    const int mb = blockIdx.y, nb = blockIdx.x;
    gemm_db(xbf + (size_t)mb * 128 * DIN, DIN,
            rwbf + (size_t)nb * 128 * DIN, DIN, DIN, smemA, smemB, acc);
    const int tid = threadIdx.x, lane = tid & 63, quad = lane >> 4, l15 = lane & 15;
    const int wm = ((tid >> 7) & 1) * 64, wn = ((tid >> 6) & 1) * 64;
    const int cbase = nb * 128;
    const int area = cbase >> 11;
    float asum = 0.f;
#pragma unroll
    for (int nt = 0; nt < 4; ++nt) {
        const int col = cbase + wn + nt * 16 + l15;
        const int n = col & (AN - 1);
        const float bias = rb[col];
#pragma unroll
        for (int mt = 0; mt < 4; ++mt) {
#pragma unroll
            for (int r = 0; r < 4; ++r) {
                const int row = mb * 128 + wm + mt * 16 + quad * 4 + r;
                const float z = tanhf(acc[mt][nt][r] + bias);
                asum += fabsf(z);
                hist0[(size_t)area * BAN + (size_t)row * AN + n] = z;
                z0[zpk2(area, row, n)] = f2bf(z);
            }
        }
    }
    for (int off = 32; off > 0; off >>= 1) asum += __shfl_down(asum, off, 64);
    if (lane == 0) red[tid >> 6] = asum;
    __syncthreads();
    if (tid == 0) atomicAdd(&gacc[area], red[0] + red[1] + red[2] + red[3]);
}

// ---- tick GEMM: 256x256 tile, BK=64, 8 waves (2x4), 2 LDS buffers, 8-phase
// schedule (T3+T4+T2+T5 per guide m201 template). grid 256 flat, 1 block/CU.
// Phase = {ds_read quadrant | stage half-tile | bar | lgkm0+SGB | prio1 | 16 MFMA | prio0 | bar}.
// K-tile k+1 staged into buf^1 during k's phases 0-1 (buf^1 holds stale k-1: safe).
// Top-of-K-tile vmcnt(0)+bar waits on loads issued >=2 phases earlier (no stall).
__global__ __launch_bounds__(512, 2)
void k_tick_mm(const u16* __restrict__ zprev, const u16* __restrict__ weff,
               const float* __restrict__ gin, float* __restrict__ zacc) {
    __shared__ __align__(16) u16 sA[2][2][8192];   // [buf][half][128x64 swizzled]
    __shared__ __align__(16) u16 sB[2][2][8192];
    const int id = blockIdx.x;                     // 256 blocks
    const int mb = id >> 7;                        // ids p and p+128 -> same XCD:
    const int panel = id & 127;                    // the 2 mb-blocks of a B panel
    const int i = panel >> 5;                      // co-locate for L2 reuse
    const int nb = panel & 31;
    const float thr = THRESHOLD * (float)BAN;
    if (!(gin[i] > thr)) return;                   // block-uniform
    const int o = nb >> 3, nb8 = nb & 7;
    const int tid = threadIdx.x, lane = tid & 63, quad = lane >> 4, l15 = lane & 15;
    const int w = tid >> 6, wr = w >> 2, wc = w & 3;
    const int cs0 = ((quad ^ (l15 & 7)) << 3);         // swizzled chunk, ks=0
    const int cs1 = (((4 | quad) ^ (l15 & 7)) << 3);   // ks=1
    const u16* Ab = zprev + (((size_t)i * 4 + mb * 2) * 32) * 8192 + tid * 8;
    const u16* Bb = weff + ((((size_t)(o * 4 + i)) * 16 + nb8 * 2) * 32) * 8192 + tid * 8;

    auto stageA = [&](int buf, int h, int kt) {
        const u16* s = Ab + ((size_t)h * 32 + kt) * 8192;
        u16* d = &sA[buf][h][tid * 8];
        load_lds16(s, d);
        load_lds16(s + 4096, d + 4096);
    };
    auto stageB = [&](int buf, int h, int kt) {
        const u16* s = Bb + ((size_t)h * 32 + kt) * 8192;
        u16* d = &sB[buf][h][tid * 8];
        load_lds16(s, d);
        load_lds16(s + 4096, d + 4096);
    };

    floatx4 acc[8][4] = {};
    bf16x8 bv[4][2];
    const int hb = wc >> 1;              // B half for this wave
    const int cb = (wc & 1) << 6;        // col base within half

    // prologue: K-tile 0 into buf 0
    stageA(0, 0, 0); stageA(0, 1, 0); stageB(0, 0, 0); stageB(0, 1, 0);

    for (int kt = 0; kt < 32; ++kt) {
        const int buf = kt & 1;
        asm volatile("s_waitcnt vmcnt(0)" ::: "memory");  // loads >=2 phases old
        __builtin_amdgcn_s_barrier();                      // all waves' stages landed
        const u16* A0 = &sA[buf][wr][0];
        const u16* B0 = &sB[buf][hb][0];
#pragma unroll
        for (int p = 0; p < 4; ++p) {
            const int r0 = (p * 2) * 16 + l15;
            const bf16x8 av0k0 = *(const bf16x8*)(A0 + r0 * 64 + cs0);
            const bf16x8 av0k1 = *(const bf16x8*)(A0 + r0 * 64 + cs1);
            const bf16x8 av1k0 = *(const bf16x8*)(A0 + (r0 + 16) * 64 + cs0);
            const bf16x8 av1k1 = *(const bf16x8*)(A0 + (r0 + 16) * 64 + cs1);
            if (p == 0) {
#pragma unroll
                for (int nt = 0; nt < 4; ++nt) {
                    const int rb2 = cb + nt * 16 + l15;
                    bv[nt][0] = *(const bf16x8*)(B0 + rb2 * 64 + cs0);
                    bv[nt][1] = *(const bf16x8*)(B0 + rb2 * 64 + cs1);
                }
            }
            if (kt + 1 < 32) {           // stage k+1 early (phases 0-1) -> slack
                if (p == 0) { stageB(buf ^ 1, 0, kt + 1); stageB(buf ^ 1, 1, kt + 1); }
                else if (p == 1) { stageA(buf ^ 1, 0, kt + 1); stageA(buf ^ 1, 1, kt + 1); }
            }
            __builtin_amdgcn_s_barrier();
            asm volatile("s_waitcnt lgkmcnt(0)" ::: "memory");
            __builtin_amdgcn_sched_barrier(0);             // rule 18
            __builtin_amdgcn_s_setprio(1);
#pragma unroll
            for (int nt = 0; nt < 4; ++nt) {
                acc[2 * p][nt] = __builtin_amdgcn_mfma_f32_16x16x32_bf16(av0k0, bv[nt][0], acc[2 * p][nt], 0, 0, 0);
                acc[2 * p][nt] = __builtin_amdgcn_mfma_f32_16x16x32_bf16(av0k1, bv[nt][1], acc[2 * p][nt], 0, 0, 0);
                acc[2 * p + 1][nt] = __builtin_amdgcn_mfma_f32_16x16x32_bf16(av1k0, bv[nt][0], acc[2 * p + 1][nt], 0, 0, 0);
                acc[2 * p + 1][nt] = __builtin_amdgcn_mfma_f32_16x16x32_bf16(av1k1, bv[nt][1], acc[2 * p + 1][nt], 0, 0, 0);
            }
            __builtin_amdgcn_s_setprio(0);
            __builtin_amdgcn_s_barrier();
        }
    }

    float* __restrict__ dst = zacc + ((size_t)i * 4 + o) * BAN;
    const int nbase = nb8 * 256;
#pragma unroll
    for (int mt = 0; mt < 8; ++mt) {
#pragma unroll
        for (int nt = 0; nt < 4; ++nt) {
            const int n = nbase + wc * 64 + nt * 16 + l15;
#pragma unroll
            for (int r = 0; r < 4; ++r) {
                const int row = mb * 256 + wr * 128 + mt * 16 + quad * 4 + r;
                dst[(size_t)row * AN + n] = acc[mt][nt][r];
            }
        }
    }
}

// ---- tick epilogue: Z = tanh(sum_i gate[i]*zacc[i][o] + gated bias) ----
__global__ void k_tick_ep(const float* __restrict__ zacc, const float* __restrict__ bblk,
                          const float* __restrict__ gin, float* __restrict__ hist,
                          u16* __restrict__ zcur, float* __restrict__ gout) {
    __shared__ float red[4];
    const int tid = threadIdx.x;
    const int t8 = (blockIdx.x * 256 + tid) * 8;   // elem index in [o][b][n]
    const int o = t8 >> 20;                        // block-uniform
    const int n = t8 & (AN - 1);
    const int io = t8 & (BAN - 1);
    const int b = io >> 11;
    const float thr = THRESHOLD * (float)BAN;
    float s[8] = {0.f, 0.f, 0.f, 0.f, 0.f, 0.f, 0.f, 0.f};
#pragma unroll
    for (int i = 0; i < 4; ++i) {
        if (!(gin[i] > thr)) continue;
        const float4* p = (const float4*)(zacc + ((size_t)i * 4 + o) * BAN + io);
        const float4 x0 = p[0], x1 = p[1];
        const float4* bb = (const float4*)(bblk + (size_t)(o * 4 + i) * AN + n);
        const float4 b0 = bb[0], b1 = bb[1];
        s[0] += x0.x + b0.x; s[1] += x0.y + b0.y; s[2] += x0.z + b0.z; s[3] += x0.w + b0.w;
        s[4] += x1.x + b1.x; s[5] += x1.y + b1.y; s[6] += x1.z + b1.z; s[7] += x1.w + b1.w;
    }
    float4 h0, h1;
    uint4 zb;
    const float z0 = tanhf(s[0]), z1 = tanhf(s[1]), z2 = tanhf(s[2]), z3 = tanhf(s[3]);
    const float z4 = tanhf(s[4]), z5 = tanhf(s[5]), z6 = tanhf(s[6]), z7 = tanhf(s[7]);
    float asum = fabsf(z0) + fabsf(z1) + fabsf(z2) + fabsf(z3)
               + fabsf(z4) + fabsf(z5) + fabsf(z6) + fabsf(z7);
    h0.x = z0; h0.y = z1; h0.z = z2; h0.w = z3;
    h1.x = z4; h1.y = z5; h1.z = z6; h1.w = z7;
    zb.x = (unsigned)f2bf(z0) | ((unsigned)f2bf(z1) << 16);
    zb.y = (unsigned)f2bf(z2) | ((unsigned)f2bf(z3) << 16);
    zb.z = (unsigned)f2bf(z4) | ((unsigned)f2bf(z5) << 16);
    zb.w = (unsigned)f2bf(z6) | ((unsigned)f2bf(z7) << 16);
    ((float4*)(hist + t8))[0] = h0;
    ((float4*)(hist + t8))[1] = h1;
    *((uint4*)(zcur + zpk2(o, b, n))) = zb;        // chunk-aligned (n%8==0)
    for (int off = 32; off > 0; off >>= 1) asum += __shfl_down(asum, off, 64);
    if ((tid & 63) == 0) red[tid >> 6] = asum;
    __syncthreads();
    if (tid == 0) atomicAdd(&gout[o], red[0] + red[1] + red[2] + red[3]);
}

// ---- scatter packed Z -> Zflat[b, area_idx[a,n]] (gather form) ----
__global__ void k_scatter(const u16* __restrict__ z4, const int* __restrict__ aidx,
                          u16* __restrict__ zflat) {
    const int i = blockIdx.x * 256 + threadIdx.x;  // [a][b][n] row-major flat
    const int a = i >> 20;
    const int b = (i >> 11) & (BATCH - 1);
    const int n = i & (AN - 1);
    zflat[(size_t)b * NTOT + aidx[a * AN + n]] = z4[zpk2(a, b, n)];
}

// ---- logits += Zflat @ Ow^T (split-K=8, atomic f32) ----
__global__ void k_out(const u16* __restrict__ zflat, const u16* __restrict__ owbf,
                      float* __restrict__ out) {
    __shared__ __align__(16) u16 smemA[8192];
    __shared__ __align__(16) u16 smemB[8192];
    floatx4 acc[4][4] = {};
    const int nb = blockIdx.x, mb = blockIdx.y, ks = blockIdx.z;
    gemm_db(zflat + (size_t)mb * 128 * NTOT + ks * 1024, NTOT,
            owbf + (size_t)nb * 128 * NTOT + ks * 1024, NTOT, 1024,
            smemA, smemB, acc);
    const int tid = threadIdx.x, lane = tid & 63, quad = lane >> 4, l15 = lane & 15;
    const int wm = ((tid >> 7) & 1) * 64, wn = ((tid >> 6) & 1) * 64;
#pragma unroll
    for (int mt = 0; mt < 4; ++mt)
#pragma unroll
        for (int nt = 0; nt < 4; ++nt)
#pragma unroll
            for (int r = 0; r < 4; ++r) {
                const int row = mb * 128 + wm + mt * 16 + quad * 4 + r;
                const int col = nb * 128 + wn + nt * 16 + l15;
                atomicAdd(&out[(size_t)row * NCLS + col], acc[mt][nt][r]);
            }
}

extern "C" void kernel_launch(void* const* d_in, const int* in_sizes, int n_in,
                              void* d_out, int out_size, void* d_ws, size_t ws_size,
                              hipStream_t stream) {
    (void)in_sizes; (void)n_in; (void)out_size; (void)ws_size;
    const float* x    = (const float*)d_in[0];
    const float* Rw   = (const float*)d_in[1];
    const float* rb   = (const float*)d_in[2];
    const float* Wb   = (const float*)d_in[3];
    const float* bblk = (const float*)d_in[4];
    const float* mask = (const float*)d_in[5];
    const float* Ow   = (const float*)d_in[6];
    const float* Ob   = (const float*)d_in[7];
    const int*   aidx = (const int*)d_in[8];

    float* out  = (float*)d_out;
    float* hist = out + (size_t)BATCH * NCLS;  // history: [5, 4, 512, 2048]

    char* ws = (char*)d_ws;
    size_t off = 0;
    auto alloc = [&](size_t bytes) -> char* {
        char* p = ws + off;
        off += (bytes + 255) & ~(size_t)255;
        return p;
    };
    u16* weffbf = (u16*)alloc((size_t)16 * AN * AN * 2);      // 128 MiB (packed v2)
    float* zacc = (float*)alloc((size_t)16 * BAN * 4);        // 67.1 MiB (aliased below)
    u16* rwbf  = (u16*)zacc;                                  // [0, 16 MiB)
    u16* owbf  = (u16*)((char*)zacc + ((size_t)16 << 20));    // [16, 32 MiB)
    u16* zflat = (u16*)((char*)zacc + ((size_t)32 << 20));    // [32, 40 MiB)
    u16* xbf    = (u16*)alloc((size_t)BATCH * DIN * 2);       // 1 MiB
    u16* zb0    = (u16*)alloc((size_t)NUM_AREAS * BAN * 2);   // 8 MiB (packed v2)
    u16* zb1    = (u16*)alloc((size_t)NUM_AREAS * BAN * 2);   // 8 MiB (packed v2)
    float* gacc = (float*)alloc(32 * 4);                      // [5][4] sums of |Z|
    u16* zb[2]  = { zb0, zb1 };

    k_init<<<(BATCH * NCLS + 255) / 256, 256, 0, stream>>>(Ob, out, gacc);
    k_cvt<<<(BATCH * DIN / 8) / 256, 256, 0, stream>>>(x, xbf, BATCH * DIN / 8);
    k_cvt<<<(NTOT * DIN / 8) / 256, 256, 0, stream>>>(Rw, rwbf, NTOT * DIN / 8);
    k_weffp<<<dim3(4, 16, 16), 256, 0, stream>>>(Wb, mask, weffbf);

    dim3 g1(64, 4);
    k_enc<<<g1, 256, 0, stream>>>(xbf, rwbf, rb, hist, zb[0], gacc);
    for (int t = 1; t <= 4; ++t) {
        k_tick_mm<<<256, 512, 0, stream>>>(zb[(t + 1) & 1], weffbf,
                                           gacc + (t - 1) * 4, zacc);
        k_tick_ep<<<2048, 256, 0, stream>>>(zacc, bblk, gacc + (t - 1) * 4,
                                            hist + (size_t)t * NUM_AREAS * BAN,
                                            zb[t & 1], gacc + t * 4);
    }
    // owbf/zflat alias zacc -> convert Ow only after ticks are done
    k_cvt<<<(NCLS * NTOT / 8) / 256, 256, 0, stream>>>(Ow, owbf, NCLS * NTOT / 8);
    // final Z is in zb[0] after 4 ticks
    k_scatter<<<(NUM_AREAS * BAN) / 256, 256, 0, stream>>>(zb[0], aidx, zflat);
    k_out<<<dim3(8, 4, 8), 256, 0, stream>>>(zflat, owbf, out);
}